// Round 2
// baseline (1243.559 us; speedup 1.0000x reference)
//
#include <hip/hip_runtime.h>
#include <math.h>

// Problem constants (from reference)
#define TT 2048
#define BB 512
#define II 11
#define HH 33
#define NL 3
#define OO 18
#define FSLOT 40          // fp32 slots per LDS vector (160 B, 16B-aligned)

typedef float f2 __attribute__((ext_vector_type(2)));

// fast sigmoid / tanh via v_exp_f32 + v_rcp_f32 (saturate correctly at +-inf)
__device__ __forceinline__ float sigm_f(float x) {
    float e = __expf(-x);
    return __builtin_amdgcn_rcpf(1.0f + e);
}
__device__ __forceinline__ float tanh_f(float x) {
    float e = __expf(2.0f * x);
    return 1.0f - 2.0f * __builtin_amdgcn_rcpf(e + 1.0f);
}

// lane<->lane^1 exchange via DPP quad_perm [1,0,3,2] (pure VALU, no LDS)
__device__ __forceinline__ float dppx1(float v) {
    return __int_as_float(__builtin_amdgcn_update_dpp(
        0, __float_as_int(v), 0xB1 /*quad_perm 1,0,3,2*/, 0xF, 0xF, true));
}

// packed fp32 FMA: acc.xy += w.xy * v.xy  (2 fp32 MACs, full-rate VOP3P --
// this is the instruction MI355X's 157.3 TF fp32 peak assumes; v_dot2_f32_f16
// measured ~quarter-rate, which was the R0/R1 bottleneck).
// asm "v" constraints force arch-VGPR operands (no AGPR copy per use).
#define PK(acc, w, v) asm("v_pk_fma_f32 %0, %1, %2, %0" : "+v"(acc) : "v"(w), "v"(v))

// Layer-pipelined LSTM, TWO LANES PER UNIT (K-split + DPP pair reduce), fused MLP.
// grid = 512 blocks (one batch element each), block = 256 threads (4 waves).
// tid < 198: unit u = tid>>1, half hf = tid&1. hf=0 owns k 0..15, hf=1 owns
//   k 16..33 of ALL 4 gate rows (input side + own-h side) => 72 v_pk_fma_f32
//   per lane as 4 independent 18-deep fp32 chains (2cy issue each).
//   Pair combine: pair-fold + 4 DPP(lane^1) adds; transcendentals split across
//   the pair (hf0: sigm(i),sigm(f); hf1: tanh(g),sigm(o)); 2 DPP moves
//   broadcast gates; both lanes compute identical c/h; hf0 writes.
// tid 200..210: x prefetchers (11 features), 2-deep software pipeline.
// LDS: ping-pong fp32 buf[2][4][FSLOT]; one barrier per superstep; peeled
// steady state with compile-time ping-pong.
__global__ __launch_bounds__(256, 1) void lstm_pipeline_kernel(
    const float* __restrict__ x,
    const float* __restrict__ Wih0, const float* __restrict__ Whh0,
    const float* __restrict__ bih0, const float* __restrict__ bhh0,
    const float* __restrict__ Wih1, const float* __restrict__ Whh1,
    const float* __restrict__ bih1, const float* __restrict__ bhh1,
    const float* __restrict__ Wih2, const float* __restrict__ Whh2,
    const float* __restrict__ bih2, const float* __restrict__ bhh2,
    const float* __restrict__ W1, const float* __restrict__ b1,
    const float* __restrict__ W2, const float* __restrict__ b2,
    float* __restrict__ hidden_out,   // [3, 512, 33]
    float* __restrict__ outp)         // [3, 512, 18]
{
    __shared__ __align__(16) float buf[2][NL + 1][FSLOT];
    __shared__ float hfin[NL][HH + 1];   // final h per layer (fp32, fused MLP)
    __shared__ float h1s[NL][4 * OO];    // MLP hidden

    const int tid = threadIdx.x;
    const int bg  = blockIdx.x;

    for (int i = tid; i < 2 * (NL + 1) * FSLOT; i += 256)
        ((float*)buf)[i] = 0.0f;

    const bool comp = (tid < 2 * 99);
    const int  u    = tid >> 1;                 // unit 0..98
    const int  hf   = tid & 1;                  // K-half: 0 -> k0..15, 1 -> k16..33
    const int  l    = (u < 33) ? 0 : (u < 66) ? 1 : 2;
    const int  j    = u - 33 * l;
    const int  koff = hf ? 16 : 0;

    const int  pi   = tid - 200;
    const bool pref = (pi >= 0) && (pi < II);
    const int  pic  = pref ? pi : 0;
    const float* xrow = x + (size_t)bg * TT * II + pic;

    // ---- per-lane weights: 4 gates x (input + own) x this lane's K-half ----
    // float2 pairs, fully unrolled static indexing -> pure registers (144 VGPR)
    f2 wI[4][9], wH[4][9];
    #pragma unroll
    for (int g = 0; g < 4; ++g) {
        #pragma unroll
        for (int r = 0; r < 9; ++r) { wI[g][r] = (f2){0.f, 0.f}; wH[g][r] = (f2){0.f, 0.f}; }
    }
    float b0 = 0.0f, b1v = 0.0f, b2v = 0.0f, b3v = 0.0f;   // bias on hf=0 only

    if (comp) {
        if (!hf) {
            const float* bip = (l == 0) ? bih0 : (l == 1) ? bih1 : bih2;
            const float* bhp = (l == 0) ? bhh0 : (l == 1) ? bhh1 : bhh2;
            b0  = bip[0 * HH + j] + bhp[0 * HH + j];
            b1v = bip[1 * HH + j] + bhp[1 * HH + j];
            b2v = bip[2 * HH + j] + bhp[2 * HH + j];
            b3v = bip[3 * HH + j] + bhp[3 * HH + j];
        }
        const float* Wi = (l == 0) ? Wih0 : (l == 1) ? Wih1 : Wih2;
        const float* Wh = (l == 0) ? Whh0 : (l == 1) ? Whh1 : Whh2;
        const int kin = (l == 0) ? II : HH;
        #pragma unroll
        for (int g = 0; g < 4; ++g) {
            const float* rw = Wi + (g * HH + j) * kin;
            const float* rh = Wh + (g * HH + j) * HH;
            #pragma unroll
            for (int r = 0; r < 9; ++r) {
                const int  k    = koff + 2 * r;
                const bool dead = (!hf) && (r == 8);   // hf0 owns only k0..15
                wI[g][r].x = (!dead && k     < kin) ? rw[k]     : 0.0f;
                wI[g][r].y = (!dead && k + 1 < kin) ? rw[k + 1] : 0.0f;
                wH[g][r].x = (!dead && k     < HH)  ? rh[k]     : 0.0f;
                wH[g][r].y = (!dead && k + 1 < HH)  ? rh[k + 1] : 0.0f;
            }
        }
    }

    // lane-constant unified nonlinearity coefs: xg = AX + BX * rcp(exp(kX*a)+1)
    //   hf=0: sigm(a0) -> kX=-1, AX=0, BX=+1      (gate i)
    //   hf=1: tanh(a2) -> kX=+2, AX=1, BX=-2      (gate g)
    const float kX = hf ? 2.0f : -1.0f;
    const float AX = hf ? 1.0f : 0.0f;
    const float BX = hf ? -2.0f : 1.0f;

    __syncthreads();
    float v_next = 0.0f, v_next2 = 0.0f;
    if (pref) {
        buf[0][0][pi] = xrow[0];
        v_next  = xrow[II];
        v_next2 = xrow[2 * II];
    }
    __syncthreads();

    float c = 0.0f;

    // hoisted ping-pong pointers (compile-time selected in peeled steps)
    const float* rin[2]  = { &buf[0][l][0],     &buf[1][l][0] };      // input vec
    const float* rown[2] = { &buf[0][l + 1][0], &buf[1][l + 1][0] };  // own-h vec
    float*       wrp[2]  = { &buf[0][l + 1][j], &buf[1][l + 1][j] };
    float*       pxp[2]  = { &buf[0][0][pic],   &buf[1][0][pic] };

    // one superstep; all bool/int args are compile-time constants at call sites
    auto step = [&](int s, int rp, bool check, bool out, bool xload, bool xstore)
        __attribute__((always_inline)) {
        const int wp = rp ^ 1;
        if (pref) {
            if (xstore) *pxp[wp] = v_next;
            v_next = v_next2;
            if (xload) v_next2 = xrow[(size_t)(s + 3) * II];
        }
        const bool active = check ? (comp && (s >= l) && (s - l < TT)) : comp;
        if (active) {
            const float* ri = rin[rp];
            const float* ro = rown[rp];
            // this lane's K-half (adjacent f2 reads merge to b128; same-address
            // broadcast within 16-lane groups -> conflict-free)
            f2 vi[9], vo[9];
            #pragma unroll
            for (int r = 0; r < 9; ++r) {
                vi[r] = *(const f2*)(ri + koff + 2 * r);
                vo[r] = *(const f2*)(ro + koff + 2 * r);
            }

            // ---- 72 v_pk_fma_f32 as 4 independent 18-deep fp32 chains ----
            f2 a0 = {b0, 0.0f}, a1 = {b1v, 0.0f}, a2 = {b2v, 0.0f}, a3 = {b3v, 0.0f};
            #pragma unroll
            for (int r = 0; r < 9; ++r) {
                PK(a0, wI[0][r], vi[r]); PK(a1, wI[1][r], vi[r]);
                PK(a2, wI[2][r], vi[r]); PK(a3, wI[3][r], vi[r]);
            }
            #pragma unroll
            for (int r = 0; r < 9; ++r) {
                PK(a0, wH[0][r], vo[r]); PK(a1, wH[1][r], vo[r]);
                PK(a2, wH[2][r], vo[r]); PK(a3, wH[3][r], vo[r]);
            }

            // ---- pair-fold + DPP reduce: gate pre-activations on BOTH lanes ----
            float s0 = a0.x + a0.y, s1 = a1.x + a1.y;
            float s2 = a2.x + a2.y, s3 = a3.x + a3.y;
            s0 += dppx1(s0); s1 += dppx1(s1);
            s2 += dppx1(s2); s3 += dppx1(s3);

            // ---- split transcendentals across the pair ----
            const float aXv = hf ? s2 : s0;
            const float eX  = __expf(kX * aXv);
            const float rX  = __builtin_amdgcn_rcpf(1.0f + eX);
            const float xg  = __builtin_fmaf(BX, rX, AX);   // hf0: i  hf1: g
            const float yg  = sigm_f(hf ? s3 : s1);         // hf0: f  hf1: o

            const float xp = dppx1(xg);
            const float yp = dppx1(yg);
            const float ig = hf ? xp : xg;
            const float fg = hf ? yp : yg;
            const float gg = hf ? xg : xp;
            const float og = hf ? yg : yp;

            // identical on both lanes of the pair (keeps exec uniform)
            c = __builtin_fmaf(fg, c, ig * gg);
            const float hnew = og * tanh_f(c);

            if (!hf) {
                *wrp[wp] = hnew;
                if (out && (s - l == TT - 1)) {
                    hidden_out[((size_t)l * BB + bg) * HH + j] = hnew;
                    hfin[l][j] = hnew;
                }
            }
        }
        __syncthreads();
    };

    // prologue (pipeline fill, masked)
    step(0, 0, true, false, true, true);
    step(1, 1, true, false, true, true);
    // steady state: s = 2..2043 as constant-rp pairs (no checks, no outputs)
    for (int s = 2; s < TT - 4; s += 2) {
        step(s,     0, false, false, true, true);
        step(s + 1, 1, false, false, true, true);
    }
    // tail of steady state + epilogue (drain + final-h outputs)
    step(TT - 4, 0, false, false, true,  true);    // s=2044 (last x load)
    step(TT - 3, 1, false, false, false, true);    // s=2045
    step(TT - 2, 0, false, false, false, true);    // s=2046 (stores x[2047])
    step(TT - 1, 1, false, true,  false, false);   // s=2047: l0 writes hT
    step(TT,     0, true,  true,  false, false);   // s=2048: l1 writes hT
    step(TT + 1, 1, true,  true,  false, false);   // s=2049: l2 writes hT

    // ---- fused MLP head (hfin visible after the last step's barrier) ----
    // h1 = gelu_exact(hfin @ W1^T + b1) [3,72]; out = h1 @ W2^T + b2 [3,18]
    if (tid < 4 * OO) {                   // 72 threads x 3 layers
        #pragma unroll
        for (int ml = 0; ml < NL; ++ml) {
            float a = b1[tid];
            #pragma unroll
            for (int k = 0; k < HH; ++k) a += hfin[ml][k] * W1[tid * HH + k];
            h1s[ml][tid] = 0.5f * a * (1.0f + erff(a * 0.70710678118654752f));
        }
    }
    __syncthreads();
    if (tid < NL * OO) {                  // 54 threads
        const int ol = tid / OO, o = tid % OO;
        float a = b2[o];
        #pragma unroll
        for (int m = 0; m < 4 * OO; ++m) a += h1s[ol][m] * W2[o * (4 * OO) + m];
        outp[((size_t)ol * BB + bg) * OO + o] = a;
    }
}

extern "C" void kernel_launch(void* const* d_in, const int* in_sizes, int n_in,
                              void* d_out, int out_size, void* d_ws, size_t ws_size,
                              hipStream_t stream) {
    const float* x    = (const float*)d_in[0];
    const float* Wih0 = (const float*)d_in[1];
    const float* Whh0 = (const float*)d_in[2];
    const float* bih0 = (const float*)d_in[3];
    const float* bhh0 = (const float*)d_in[4];
    const float* Wih1 = (const float*)d_in[5];
    const float* Whh1 = (const float*)d_in[6];
    const float* bih1 = (const float*)d_in[7];
    const float* bhh1 = (const float*)d_in[8];
    const float* Wih2 = (const float*)d_in[9];
    const float* Whh2 = (const float*)d_in[10];
    const float* bih2 = (const float*)d_in[11];
    const float* bhh2 = (const float*)d_in[12];
    const float* W1   = (const float*)d_in[13];
    const float* b1   = (const float*)d_in[14];
    const float* W2   = (const float*)d_in[15];
    const float* b2   = (const float*)d_in[16];

    float* out    = (float*)d_out;                 // [3,512,18] = 27648 floats
    float* hidden = out + NL * BB * OO;            // [3,512,33] = 50688 floats

    lstm_pipeline_kernel<<<BB, 256, 0, stream>>>(
        x, Wih0, Whh0, bih0, bhh0, Wih1, Whh1, bih1, bhh1,
        Wih2, Whh2, bih2, bhh2, W1, b1, W2, b2, hidden, out);
}